// Round 1
// baseline (145.545 us; speedup 1.0000x reference)
//
#include <hip/hip_runtime.h>
#include <hip/hip_bf16.h>
#include <stdint.h>

#define LN_EPS 1e-5f

typedef __attribute__((ext_vector_type(4))) float f32x4;
typedef __attribute__((ext_vector_type(8))) short bf16x8;

#define B_ 8
#define S_ 4096
#define D_ 1024
#define P_ 512
#define N_ (B_*S_)   // 32768 rows

// async global->LDS, 16B per lane
__device__ __forceinline__ void gload_lds16(const void* gsrc, void* ldst) {
  __builtin_amdgcn_global_load_lds(
      (const __attribute__((address_space(1))) void*)gsrc,
      (__attribute__((address_space(3))) void*)ldst,
      16, 0, 0);
}

// ---------------- kernel 1: zero W2f / b2 ----------------
__global__ void k_zero(float* __restrict__ w2f, float* __restrict__ b2) {
  int i = blockIdx.x * 256 + threadIdx.x;
  if (i < D_ * P_) w2f[i] = 0.f;
  if (i < D_) b2[i] = 0.f;
}

// ---------------- kernel 2: scatter W rows into W2f ----------------
// W2f[c,p] = sum_{d: s5[d]==c} W[d,p];  b2[c] = sum_{d: s5[d]==c} b[d]
__global__ void k_scatter(const float* __restrict__ W, const float* __restrict__ bias,
                          const int* __restrict__ s5,
                          float* __restrict__ w2f, float* __restrict__ b2) {
  int d = blockIdx.x;                  // 0..1023
  int c = s5[d];
  const float* wrow = W + (size_t)d * P_;
  float* dst = w2f + (size_t)c * P_;
  for (int p = threadIdx.x; p < P_; p += 256)
    atomicAdd(&dst[p], wrow[p]);
  if (threadIdx.x == 0) atomicAdd(&b2[c], bias[d]);
}

// ---------------- kernel 3: W2f -> bf16 ----------------
__global__ void k_conv(const float* __restrict__ w2f, __hip_bfloat16* __restrict__ w2b) {
  int i = blockIdx.x * 256 + threadIdx.x;
  if (i < D_ * P_) w2b[i] = __float2bfloat16(w2f[i]);
}

// ---------------- kernel 4: LayerNorm + gather -> g (bf16 [N_,P_]) ----------------
__global__ __launch_bounds__(256) void k_ln_gather(
    const float* __restrict__ x, const float* __restrict__ lnw,
    const float* __restrict__ lnb, const int* __restrict__ s3,
    __hip_bfloat16* __restrict__ g) {
  __shared__ float row[D_];
  __shared__ float psum[4], psum2[4];
  const int n = blockIdx.x;
  const int t = threadIdx.x;
  const float* xr = x + (size_t)n * D_;
  float4 v = ((const float4*)xr)[t];       // 256 threads * 4 floats = 1024
  ((float4*)row)[t] = v;
  float s  = v.x + v.y + v.z + v.w;
  float s2 = v.x*v.x + v.y*v.y + v.z*v.z + v.w*v.w;
  #pragma unroll
  for (int off = 32; off > 0; off >>= 1) {
    s  += __shfl_down(s, off);
    s2 += __shfl_down(s2, off);
  }
  const int lane = t & 63, wid = t >> 6;
  if (lane == 0) { psum[wid] = s; psum2[wid] = s2; }
  __syncthreads();
  const float tot  = psum[0] + psum[1] + psum[2] + psum[3];
  const float tot2 = psum2[0] + psum2[1] + psum2[2] + psum2[3];
  const float mu  = tot * (1.f / D_);
  const float var = tot2 * (1.f / D_) - mu * mu;
  const float inv = rsqrtf(var + LN_EPS);
  __hip_bfloat16* gr = g + (size_t)n * P_;
  for (int p = t; p < P_; p += 256) {
    int src = s3[p];
    float val = (row[src] - mu) * inv * lnw[src] + lnb[src];
    gr[p] = __float2bfloat16(val);
  }
}

// ---------------- kernel 5: bf16 MFMA GEMM + residual + bias ----------------
// out[n,c] = hid[n,c] + sum_p g[n,p]*W2[c,p] + b2[c]
// 128x128 tile, BK=64, 4 waves (2x2), 16x16x32 bf16 MFMA, acc 4x4 frags/wave.
// LDS tiles row-major [128][64] bf16 (128B rows) with XOR swizzle byte^=((row&7)<<4);
// swizzle applied on the *global source* address (global_load_lds writes linearly)
// and on the ds_read address (both-sides rule).
#define BM 128
#define BN 128
#define BK 64

__global__ __launch_bounds__(256) void k_gemm(
    const __hip_bfloat16* __restrict__ g,    // [N_,P_]
    const __hip_bfloat16* __restrict__ w2b,  // [D_,P_]
    const float* __restrict__ b2,            // [D_]
    const float* __restrict__ hid,           // [N_,D_]
    float* __restrict__ out) {               // [N_,D_]
  __shared__ char At[BM * BK * 2];
  __shared__ char Bt[BN * BK * 2];
  const int bn = blockIdx.x * BN;   // col tile (8) — fast-moving for A-strip L2/L3 reuse
  const int bm = blockIdx.y * BM;   // row tile (256)
  const int t = threadIdx.x;
  const int lane = t & 63;
  const int wid = t >> 6;
  const int wrow = wid >> 1, wcol = wid & 1;

  f32x4 acc[4][4] = {};

  for (int k0 = 0; k0 < P_; k0 += BK) {
    __syncthreads();
    #pragma unroll
    for (int i = 0; i < 4; ++i) {
      int ch = t + i * 256;                 // chunk 0..1023, 16B each
      int r  = ch >> 3;                     // tile row (8 chunks of 16B per 128B row)
      int cc = ch & 7;
      int col = ((cc ^ (r & 7)) << 3);      // pre-swizzled source col (bf16 units)
      gload_lds16(g   + (size_t)(bm + r) * P_ + k0 + col, At + ch * 16);
      gload_lds16(w2b + (size_t)(bn + r) * P_ + k0 + col, Bt + ch * 16);
    }
    __syncthreads();   // drains vmcnt before compute
    #pragma unroll
    for (int kk = 0; kk < 2; ++kk) {
      bf16x8 af[4], bfr[4];
      const int colb = kk * 64 + ((lane >> 4) << 4);   // byte offset within row
      #pragma unroll
      for (int mi = 0; mi < 4; ++mi) {
        int r = wrow * 64 + mi * 16 + (lane & 15);
        af[mi] = *(const bf16x8*)(At + ((r * 128 + colb) ^ ((r & 7) << 4)));
      }
      #pragma unroll
      for (int ni = 0; ni < 4; ++ni) {
        int r = wcol * 64 + ni * 16 + (lane & 15);
        bfr[ni] = *(const bf16x8*)(Bt + ((r * 128 + colb) ^ ((r & 7) << 4)));
      }
      #pragma unroll
      for (int mi = 0; mi < 4; ++mi)
        #pragma unroll
        for (int ni = 0; ni < 4; ++ni)
          acc[mi][ni] = __builtin_amdgcn_mfma_f32_16x16x32_bf16(af[mi], bfr[ni], acc[mi][ni], 0, 0, 0);
    }
  }

  // epilogue: C/D layout col=lane&15 (N), row=(lane>>4)*4+reg (M)
  const int row0 = bm + wrow * 64 + ((lane >> 4) << 2);
  const int col0 = bn + wcol * 64 + (lane & 15);
  #pragma unroll
  for (int ni = 0; ni < 4; ++ni) {
    const int col = col0 + ni * 16;
    const float bias = b2[col];
    #pragma unroll
    for (int mi = 0; mi < 4; ++mi) {
      const int rw = row0 + mi * 16;
      #pragma unroll
      for (int r = 0; r < 4; ++r) {
        size_t idx = (size_t)(rw + r) * D_ + col;
        out[idx] = hid[idx] + acc[mi][ni][r] + bias;
      }
    }
  }
}

extern "C" void kernel_launch(void* const* d_in, const int* in_sizes, int n_in,
                              void* d_out, int out_size, void* d_ws, size_t ws_size,
                              hipStream_t stream) {
  const float* hid  = (const float*)d_in[0];
  const float* lnw  = (const float*)d_in[1];
  const float* lnb  = (const float*)d_in[2];
  const float* W    = (const float*)d_in[3];
  const float* bias = (const float*)d_in[4];
  const int*   s3   = (const int*)d_in[5];
  const int*   s5   = (const int*)d_in[6];
  float* out = (float*)d_out;

  // workspace layout (all 256B-aligned):
  //   [0, 2MB)        W2f  fp32 [1024][512]
  //   [2MB, +4KB)     b2   fp32 [1024]
  //   [2MB+4KB, +1MB) W2b  bf16 [1024][512]
  //   [3MB+4KB, +32MB) g   bf16 [32768][512]
  char* ws = (char*)d_ws;
  float*          w2f = (float*)ws;
  float*          b2  = (float*)(ws + 2097152);
  __hip_bfloat16* w2b = (__hip_bfloat16*)(ws + 2101248);
  __hip_bfloat16* g   = (__hip_bfloat16*)(ws + 3149824);

  k_zero   <<<dim3(2048), dim3(256), 0, stream>>>(w2f, b2);
  k_scatter<<<dim3(1024), dim3(256), 0, stream>>>(W, bias, s5, w2f, b2);
  k_conv   <<<dim3(2048), dim3(256), 0, stream>>>(w2f, w2b);
  k_ln_gather<<<dim3(N_), dim3(256), 0, stream>>>(hid, lnw, lnb, s3, g);
  k_gemm   <<<dim3(D_/BN, N_/BM), dim3(256), 0, stream>>>(g, w2b, b2, hid, out);
}